// Round 9
// baseline (282.663 us; speedup 1.0000x reference)
//
#include <hip/hip_runtime.h>
#include <hip/hip_bf16.h>

// RSFConv2d round 9: two-pass.
//  Pass 1 (xform): NCHW fp32 -> 4 channel-octet bf16 planes [c8][n][y][x][8bf16]
//    (16 B per px per plane). Pure streaming, no LDS/barriers.
//  Pass 2 (conv): stage via global_load_lds_dwordx4 with per-lane SWIZZLED
//    SOURCE addresses (linear LDS dest, m173 pattern) -- staging has ~0 VALU,
//    no ds_write (R8's 8.6e6 write-side conflicts vanish). Compute/epilogue
//    identical to R8 (32x32x16 MFMA, exact wh+wl weight split, full-line
//    nontemporal stores, XCD-bijective y-fastest block swizzle).
//  R8 post-mortem: 4 structural variants all ~210us with every pipe <16% busy
//  -- stage convoy latency + fp32 32-plane gather was the un-hideable cost.
//  Fallback: if ws_size < 134.3 MB, run the R8 kernel (conv_fb).

typedef __attribute__((ext_vector_type(8))) short bf16x8;
typedef __attribute__((ext_vector_type(16))) float f32x16;
typedef __attribute__((ext_vector_type(4))) unsigned int u32x4;
typedef __attribute__((ext_vector_type(4))) float f32x4v;

__device__ __forceinline__ unsigned short f2bf(float f) {
    unsigned u = __float_as_uint(f);
    u = u + 0x7fffu + ((u >> 16) & 1u);  // RNE
    return (unsigned short)(u >> 16);
}
__device__ __forceinline__ float bf2f(unsigned short b) {
    return __uint_as_float(((unsigned)b) << 16);
}

// ---------------- kernel synthesis: one thread per (o,i) pair ----------------
__global__ __launch_bounds__(256) void prep_kernel(const float* __restrict__ fw,
                                                   unsigned short* __restrict__ wbuf)
{
    int gid = blockIdx.x * blockDim.x + threadIdx.x;
    if (gid >= 32 * 32) return;
    int o = gid >> 5;
    int i = gid & 31;

    // zero block for OOB global_load_lds sources (byte 36864..36927 of ws)
    if (gid < 16) ((unsigned*)(wbuf + 18432))[gid] = 0u;

    const float* f = fw + (size_t)gid * 12;
    float re[3][2], im[3][2];
#pragma unroll
    for (int ky = 0; ky < 3; ++ky)
#pragma unroll
        for (int kx = 0; kx < 2; ++kx) {
            re[ky][kx] = f[(ky * 2 + kx) * 2 + 0];
            im[ky][kx] = f[(ky * 2 + kx) * 2 + 1];
        }

    const float c3[3] = {1.f, -0.5f, -0.5f};
    const float s3[3] = {0.f, 0.86602540378443864676f, -0.86602540378443864676f};

    float base[3][3];
#pragma unroll
    for (int y = 0; y < 3; ++y)
#pragma unroll
        for (int x = 0; x < 3; ++x) {
            float sum = 0.f;
#pragma unroll
            for (int ky = 0; ky < 3; ++ky)
#pragma unroll
                for (int kx = 0; kx < 3; ++kx) {
                    float rf, mf;
                    if (kx < 2) {
                        rf = re[ky][kx];
                        mf = im[ky][kx];
                    } else {
                        int kys = (3 - ky) % 3;
                        rf = re[kys][1];
                        mf = -im[kys][1];
                    }
                    int m = (ky * y + kx * x) % 3;
                    sum += rf * c3[m] - mf * s3[m];
                }
            base[y][x] = sum * (1.f / 9.f);
        }

    const float scales[4] = {1.f, 1.25f, 1.5625f, 1.953125f};
    const float coords[3] = {-2.f / 3.f, 0.f, 2.f / 3.f};

    float acc[3][3] = {{0.f, 0.f, 0.f}, {0.f, 0.f, 0.f}, {0.f, 0.f, 0.f}};

    for (int t = 0; t < 32; ++t) {
        int r = t >> 2, si = t & 3;
        float th = (float)r * 0.78539816339744830961f;
        float sc = scales[si];
        float c = cosf(th) * sc;
        float s = sinf(th) * sc;
#pragma unroll
        for (int p = 0; p < 3; ++p) {
#pragma unroll
            for (int q = 0; q < 3; ++q) {
                float gxo = coords[q], gyo = coords[p];
                float gx = c * gxo - s * gyo;
                float gy = s * gxo + c * gyo;
                float ix = ((gx + 1.f) * 3.f - 1.f) * 0.5f;
                float iy = ((gy + 1.f) * 3.f - 1.f) * 0.5f;
                float fx0 = floorf(ix), fy0 = floorf(iy);
                int x0 = (int)fx0, y0 = (int)fy0;
                int x1 = x0 + 1, y1 = y0 + 1;
                float wx1 = ix - fx0, wy1 = iy - fy0;
                float wx0 = 1.f - wx1, wy0 = 1.f - wy1;

                float v = 0.f;
                {
                    int yc = min(max(y0, 0), 2), xc = min(max(x0, 0), 2);
                    bool ok = (x0 >= 0) & (x0 < 3) & (y0 >= 0) & (y0 < 3);
                    v += (ok ? base[yc][xc] : 0.f) * (wy0 * wx0);
                }
                {
                    int yc = min(max(y0, 0), 2), xc = min(max(x1, 0), 2);
                    bool ok = (x1 >= 0) & (x1 < 3) & (y0 >= 0) & (y0 < 3);
                    v += (ok ? base[yc][xc] : 0.f) * (wy0 * wx1);
                }
                {
                    int yc = min(max(y1, 0), 2), xc = min(max(x0, 0), 2);
                    bool ok = (x0 >= 0) & (x0 < 3) & (y1 >= 0) & (y1 < 3);
                    v += (ok ? base[yc][xc] : 0.f) * (wy1 * wx0);
                }
                {
                    int yc = min(max(y1, 0), 2), xc = min(max(x1, 0), 2);
                    bool ok = (x1 >= 0) & (x1 < 3) & (y1 >= 0) & (y1 < 3);
                    v += (ok ? base[yc][xc] : 0.f) * (wy1 * wx1);
                }
                acc[p][q] += v;
            }
        }
    }

    // wbuf[(tap*2+hl)*1024 + o*32 + i]: A rows = o, k = i.
#pragma unroll
    for (int p = 0; p < 3; ++p)
#pragma unroll
        for (int q = 0; q < 3; ++q) {
            int t = p * 3 + q;
            float w = acc[p][q] * (1.f / 32.f);
            unsigned short wh = f2bf(w);
            unsigned short wl = f2bf(w - bf2f(wh));
            size_t b = (size_t)(t * 2) * 1024 + o * 32 + i;
            wbuf[b] = wh;
            wbuf[b + 1024] = wl;
        }
}

// ---------------- pass 1: NCHW fp32 -> octet bf16 planes ----------------
// xw plane c (c=0..3): channels 8c..8c+7, [n][y][x] 16 B per px.
__global__ __launch_bounds__(256) void xform(const float* __restrict__ x,
                                             unsigned short* __restrict__ xw)
{
    const int b = blockIdx.x;             // 8192 = 8n * 512y * 2h
    const int n = b >> 10;
    const int r = b & 1023;
    const int y = r >> 1;
    const int h = r & 1;
    const int tid = threadIdx.x;
    const int c = tid >> 6;               // octet
    const int lane = tid & 63;
    const int px0 = h * 256 + lane * 4;

    const float* src = x + ((size_t)n << 23) + (((size_t)(c * 8)) << 18) + (y << 9) + px0;
    float v[8][4];
#pragma unroll
    for (int cc = 0; cc < 8; ++cc) {
        f32x4v ld = *(const f32x4v*)(src + ((size_t)cc << 18));
#pragma unroll
        for (int j = 0; j < 4; ++j) v[cc][j] = ld[j];
    }
    char* dst = (char*)xw + (((size_t)c << 25)) +
                ((((size_t)(n << 9) + y) << 9) + px0) * 16;
#pragma unroll
    for (int j = 0; j < 4; ++j) {
        u32x4 d;
#pragma unroll
        for (int p = 0; p < 4; ++p)
            d[p] = (unsigned)f2bf(v[2 * p][j]) | ((unsigned)f2bf(v[2 * p + 1][j]) << 16);
        *(u32x4*)(dst + j * 16) = d;
    }
}

// ---------------- pass 2: conv, 8x32 tile, 4 waves, 32x32x16 MFMA ----------------
#define TLH 8
#define TLW 32
#define LCOLS 34
#define NPX 340  // 10*34 halo pixels, 64 B each

// read swizzle: slot k for (px,c): k = c ^ ((px>>1)&3); any 8 consecutive px
// cover all 8 16B bank phases.
__device__ __forceinline__ unsigned lds_byte(int px, int c) {
    return ((unsigned)px << 6) + ((((unsigned)(px >> 1) & 3u) ^ (unsigned)c) << 4);
}

__global__ __launch_bounds__(256, 6) void conv_mfma(const unsigned short* __restrict__ xw,
                                                    const unsigned short* __restrict__ wbuf,
                                                    const char* __restrict__ zbuf,
                                                    float* __restrict__ out)
{
    __shared__ unsigned slds[6144];  // 24576 B (1536 chunks of 16 B, padded)

    // flat grid 8192; bijective XCD swizzle, y-fastest (XCD k = image k)
    const int lin = blockIdx.x;
    const int s0 = (lin & 7) * 1024 + (lin >> 3);
    const int n = s0 >> 10;
    const int rem = s0 & 1023;
    const int y0t = (rem & 63) * TLH;
    const int x0t = (rem >> 6) * TLW;

    const int tid = threadIdx.x;

    // ---- stage: 1360 chunks (10 rows x 34 px x 4 slots) via global_load_lds ----
    // LDS dest is linear (chunk s at byte 16s); source chunk = (px, c) with
    // c = k ^ ((px>>1)&3) -> LDS layout == lds_byte() swizzle. OOB -> zbuf.
    {
        const unsigned wavebase = (unsigned)(tid & ~63);
#pragma unroll
        for (int it = 0; it < 6; ++it) {
            int s = tid + it * 256;
            int px = s >> 2;
            int k = s & 3;
            int row = px / LCOLS;
            int col = px - row * LCOLS;
            int gy = y0t + row - 1;
            int gx = x0t + col - 1;
            bool ok = (s < 1360) & ((unsigned)gy < 512u) & ((unsigned)gx < 512u);
            int c = k ^ ((px >> 1) & 3);
            const char* gsrc = ok
                ? (const char*)xw + (((size_t)c << 25)) +
                      ((((size_t)(n << 9) + gy) << 9) + gx) * 16
                : zbuf;
            unsigned ldsoff = (it * 256 + wavebase) * 16;  // wave-uniform
            __builtin_amdgcn_global_load_lds(
                (const __attribute__((address_space(1))) unsigned*)gsrc,
                (__attribute__((address_space(3))) unsigned*)((char*)slds + ldsoff),
                16, 0, 0);
        }
    }
    __syncthreads();

    // ---- MFMA: wave wv owns out rows {2wv, 2wv+1}, all 32 o ----
    const int lane = tid & 63;
    const int wv = tid >> 6;    // 0..3
    const int pxl = lane & 31;  // B col = pixel
    const int kh = lane >> 5;   // B k-half
    const int r0 = wv << 1;

    f32x16 acc[2];
#pragma unroll
    for (int f = 0; f < 2; ++f)
#pragma unroll
        for (int r = 0; r < 16; ++r) acc[f][r] = 0.f;

#pragma unroll 1
    for (int dy = 0; dy < 3; ++dy) {
        bf16x8 A[3][2][2];  // [dx][hl][kstep]
#pragma unroll
        for (int dx = 0; dx < 3; ++dx)
#pragma unroll
            for (int hl = 0; hl < 2; ++hl)
#pragma unroll
                for (int ks = 0; ks < 2; ++ks) {
                    int tap = dy * 3 + dx;
                    A[dx][hl][ks] = *(const bf16x8*)(wbuf + (size_t)(tap * 2 + hl) * 1024 +
                                                     pxl * 32 + ks * 16 + kh * 8);
                }
#pragma unroll
        for (int f = 0; f < 2; ++f) {
            int lrow = r0 + f + dy;
#pragma unroll
            for (int dx = 0; dx < 3; ++dx) {
                int px = lrow * LCOLS + dx + pxl;
#pragma unroll
                for (int ks = 0; ks < 2; ++ks) {
                    bf16x8 b = *(const bf16x8*)((const char*)slds + lds_byte(px, ks * 2 + kh));
                    acc[f] = __builtin_amdgcn_mfma_f32_32x32x16_bf16(A[dx][0][ks], b, acc[f], 0, 0, 0);
                    acc[f] = __builtin_amdgcn_mfma_f32_32x32x16_bf16(A[dx][1][ks], b, acc[f], 0, 0, 0);
                }
            }
        }
    }

#pragma unroll
    for (int f = 0; f < 2; ++f) {
        int gy = y0t + r0 + f;
#pragma unroll
        for (int reg = 0; reg < 16; ++reg) {
            int o = (reg & 3) + 8 * (reg >> 2) + 4 * kh;
            size_t idx = ((size_t)(n * 32 + o) << 18) + (size_t)(gy << 9) + x0t + pxl;
            __builtin_nontemporal_store(acc[f][reg], &out[idx]);
        }
    }
}

// ---------------- fallback (R8): staged from fp32 x directly ----------------
__global__ __launch_bounds__(256, 8) void conv_fb(const float* __restrict__ x,
                                                  const unsigned short* __restrict__ wbuf,
                                                  float* __restrict__ out)
{
    __shared__ unsigned slds[NPX * 16];

    const int lin = blockIdx.x;
    const int s = (lin & 7) * 1024 + (lin >> 3);
    const int n = s >> 10;
    const int rem = s & 1023;
    const int y0t = (rem & 63) * TLH;
    const int x0t = (rem >> 6) * TLW;

    const int tid = threadIdx.x;
    const float* xn = x + ((size_t)n << 23);

    for (int t = tid; t < 320 + 80; t += 256) {
        if (t < 320) {
            int c = t / 80;
            int rem2 = t - c * 80;
            int row = rem2 >> 3;
            int q = rem2 & 7;
            int gy = y0t + row - 1;
            int gx0 = x0t + (q << 2);
            float v[8][4];
            if ((unsigned)gy < 512u) {
                const float* src = xn + (((size_t)c << 3) << 18) + ((gy << 9) + gx0);
#pragma unroll
                for (int cc = 0; cc < 8; ++cc) {
                    f32x4v ld = *(const f32x4v*)(src + ((size_t)cc << 18));
#pragma unroll
                    for (int j = 0; j < 4; ++j) v[cc][j] = ld[j];
                }
            } else {
#pragma unroll
                for (int cc = 0; cc < 8; ++cc)
#pragma unroll
                    for (int j = 0; j < 4; ++j) v[cc][j] = 0.f;
            }
            int px0 = row * LCOLS + 1 + (q << 2);
#pragma unroll
            for (int j = 0; j < 4; ++j) {
                u32x4 d;
#pragma unroll
                for (int p = 0; p < 4; ++p)
                    d[p] = (unsigned)f2bf(v[2 * p][j]) | ((unsigned)f2bf(v[2 * p + 1][j]) << 16);
                *(u32x4*)((char*)slds + lds_byte(px0 + j, c)) = d;
            }
        } else {
            int sidx = t - 320;
            int c = sidx / 20;
            int rem2 = sidx - c * 20;
            int row = rem2 >> 1;
            int side = rem2 & 1;
            int gy = y0t + row - 1;
            int gx = x0t + (side ? 32 : -1);
            bool ok = ((unsigned)gy < 512u) & ((unsigned)gx < 512u);
            u32x4 d;
#pragma unroll
            for (int p = 0; p < 4; ++p) {
                float f0 = 0.f, f1 = 0.f;
                if (ok) {
                    const float* srcp = xn + (((size_t)(c * 8 + 2 * p)) << 18) + ((gy << 9) + gx);
                    f0 = srcp[0];
                    f1 = srcp[(size_t)1 << 18];
                }
                d[p] = (unsigned)f2bf(f0) | ((unsigned)f2bf(f1) << 16);
            }
            int px = row * LCOLS + (side ? 33 : 0);
            *(u32x4*)((char*)slds + lds_byte(px, c)) = d;
        }
    }
    __syncthreads();

    const int lane = tid & 63;
    const int wv = tid >> 6;
    const int pxl = lane & 31;
    const int kh = lane >> 5;
    const int r0 = wv << 1;

    f32x16 acc[2];
#pragma unroll
    for (int f = 0; f < 2; ++f)
#pragma unroll
        for (int r = 0; r < 16; ++r) acc[f][r] = 0.f;

#pragma unroll 1
    for (int dy = 0; dy < 3; ++dy) {
        bf16x8 A[3][2][2];
#pragma unroll
        for (int dx = 0; dx < 3; ++dx)
#pragma unroll
            for (int hl = 0; hl < 2; ++hl)
#pragma unroll
                for (int ks = 0; ks < 2; ++ks) {
                    int tap = dy * 3 + dx;
                    A[dx][hl][ks] = *(const bf16x8*)(wbuf + (size_t)(tap * 2 + hl) * 1024 +
                                                     pxl * 32 + ks * 16 + kh * 8);
                }
#pragma unroll
        for (int f = 0; f < 2; ++f) {
            int lrow = r0 + f + dy;
#pragma unroll
            for (int dx = 0; dx < 3; ++dx) {
                int px = lrow * LCOLS + dx + pxl;
#pragma unroll
                for (int ks = 0; ks < 2; ++ks) {
                    bf16x8 b = *(const bf16x8*)((const char*)slds + lds_byte(px, ks * 2 + kh));
                    acc[f] = __builtin_amdgcn_mfma_f32_32x32x16_bf16(A[dx][0][ks], b, acc[f], 0, 0, 0);
                    acc[f] = __builtin_amdgcn_mfma_f32_32x32x16_bf16(A[dx][1][ks], b, acc[f], 0, 0, 0);
                }
            }
        }
    }

#pragma unroll
    for (int f = 0; f < 2; ++f) {
        int gy = y0t + r0 + f;
#pragma unroll
        for (int reg = 0; reg < 16; ++reg) {
            int o = (reg & 3) + 8 * (reg >> 2) + 4 * kh;
            size_t idx = ((size_t)(n * 32 + o) << 18) + (size_t)(gy << 9) + x0t + pxl;
            __builtin_nontemporal_store(acc[f][reg], &out[idx]);
        }
    }
}

extern "C" void kernel_launch(void* const* d_in, const int* in_sizes, int n_in,
                              void* d_out, int out_size, void* d_ws, size_t ws_size,
                              hipStream_t stream) {
    const float* x = (const float*)d_in[0];
    const float* fw = (const float*)d_in[1];
    float* out = (float*)d_out;
    unsigned short* wbuf = (unsigned short*)d_ws;            // 36864 B weights
    const char* zbuf = (const char*)d_ws + 36864;            // 64 B zeros
    unsigned short* xw = (unsigned short*)((char*)d_ws + 40960);  // 134.2 MB planes

    prep_kernel<<<dim3(4), 256, 0, stream>>>(fw, wbuf);

    if (ws_size >= 40960ull + (1ull << 27)) {
        xform<<<dim3(8192), 256, 0, stream>>>(x, xw);
        conv_mfma<<<dim3(8192), 256, 0, stream>>>(xw, wbuf, zbuf, out);
    } else {
        conv_fb<<<dim3(8192), 256, 0, stream>>>(x, wbuf, out);
    }
}